// Round 12
// baseline (362.261 us; speedup 1.0000x reference)
//
#include <hip/hip_runtime.h>
#include <hip/hip_bf16.h>

typedef __hip_bfloat16 bf16;
typedef __attribute__((ext_vector_type(8))) short short8;
typedef __attribute__((ext_vector_type(4))) float f32x4;
typedef unsigned short ushort_t;

#define PI_F 3.14159265358979323846f
#define GPAD_Z 3111696L  // 1764*1764

#define GLOAD_LDS16(gp, lp)                                                    \
  __builtin_amdgcn_global_load_lds(                                            \
      (const __attribute__((address_space(1))) unsigned int*)(gp),             \
      (__attribute__((address_space(3))) unsigned int*)(lp), 16, 0, 0)

// ---------------------------------------------------------------------------
// K1: downsample (::2,::2) + transpose to [slice][q][384] bf16 with the
// three-term double-bf16 layout:
//   A-side (PTe): [hi | lo | hi],  B-side (MTe): [hi | hi | lo]
// so dot_{k<384} = hiA·hiB + loA·hiB + hiA·loB  (only loA·loB ~2^-18 dropped).
// Also per-pixel squared channel norms SQ[z][q] (fp32) for left/right.
// ---------------------------------------------------------------------------
__global__ __launch_bounds__(128) void prep_pt(const float* __restrict__ left,
                                               const float* __restrict__ right,
                                               const float* __restrict__ mid,
                                               bf16* __restrict__ PTe,
                                               bf16* __restrict__ MTe,
                                               float* __restrict__ SQ) {
  int q = blockIdx.x;          // 0..1599
  int y = blockIdx.y;          // 0..5
  int c = threadIdx.x;         // 0..127
  int qi = q / 40, qj = q - qi * 40;
  const float* src;
  bf16* dst;
  int b;
  bool aside = (y < 4);
  if (aside) {
    b = y & 1;
    src = (y < 2) ? left : right;
    dst = PTe + (long)y * 1664 * 384;
  } else {
    b = y - 4;
    src = mid;
    dst = MTe + (long)(y - 4) * 1664 * 384;
  }
  float v = src[(((long)b * 128 + c) * 80 + 2 * qi) * 80 + 2 * qj];
  bf16 hi = __float2bfloat16(v);
  bf16 lo = __float2bfloat16(v - __bfloat162float(hi));
  if (aside) {
    dst[(long)q * 384 + c] = hi;
    dst[(long)q * 384 + 128 + c] = lo;
    dst[(long)q * 384 + 256 + c] = hi;
  } else {
    dst[(long)q * 384 + c] = hi;
    dst[(long)q * 384 + 128 + c] = hi;
    dst[(long)q * 384 + 256 + c] = lo;
  }
  if (aside) {
    __shared__ float red[128];
    red[c] = v * v;
    __syncthreads();
    for (int s = 64; s > 0; s >>= 1) {
      if (c < s) red[c] += red[c + s];
      __syncthreads();
    }
    if (c == 0) SQ[y * 1600 + q] = red[0];
  }
}

// ---------------------------------------------------------------------------
// K2: invN[z][q] = rsqrt( 3x3 box of SQ (zero-padded) + 1152*EPS )
// ---------------------------------------------------------------------------
__global__ void invn_kernel(const float* __restrict__ SQ, float* __restrict__ INV) {
  int idx = blockIdx.x * 256 + threadIdx.x;
  if (idx >= 6400) return;
  int z = idx / 1600, q = idx - z * 1600;
  int qi = q / 40, qj = q - qi * 40;
  float s = 0.1152f;  // 128*3*3 * 1e-4
  #pragma unroll
  for (int di = -1; di <= 1; ++di)
    #pragma unroll
    for (int dj = -1; dj <= 1; ++dj) {
      int a = qi + di, b = qj + dj;
      if (a >= 0 && a < 40 && b >= 0 && b < 40) s += SQ[z * 1600 + a * 40 + b];
    }
  INV[idx] = rsqrtf(s);
}

// ---------------------------------------------------------------------------
// K3/K9: bf16 MFMA GEMM (m97 structure, BK=32, VGPR-64 epilogue) with
// XCD-aware block swizzle: when tile count % 8 == 0, remap linear tile id so
// each XCD (id%8 round-robin) owns a CONTIGUOUS chunk with M fastest-varying
// -> all blocks on an XCD share 1-2 B-tiles (L2-resident) instead of all.
// bmod=1: B slice index = z&1. cpad=1: write C into padded [42,42,42,42].
// ---------------------------------------------------------------------------
__global__ __launch_bounds__(256) void gemm_nt(const bf16* __restrict__ A,
                                               const bf16* __restrict__ B,
                                               float* __restrict__ C,
                                               int M, int N, int K,
                                               long Az, long Bz, long Cz,
                                               int bmod, int cpad) {
  int z = blockIdx.z;
  A += (long)z * Az;
  B += (long)(bmod ? (z & 1) : z) * Bz;
  C += (long)z * Cz;
  // XCD swizzle (identity when tiles % 8 != 0)
  int bx = blockIdx.x, by = blockIdx.y;
  int total = gridDim.x * gridDim.y;
  if ((total & 7) == 0) {
    int tid = bx + gridDim.x * by;
    int g = ((tid & 7) * (total >> 3)) + (tid >> 3);
    bx = g % gridDim.x;
    by = g / gridDim.x;
  }
  __shared__ bf16 As[128 * 32];  // row-major [row][32], 64 B rows, 8 KB
  __shared__ bf16 Bs[128 * 32];
  int lane = threadIdx.x & 63;
  int w = threadIdx.x >> 6;
  int mb = bx * 128;
  int nb = by * 128;
  int lr = lane >> 2;
  int gb = (lane & 3) ^ ((lane >> 3) & 3);  // XOR swizzle at stage time
  int lm = lane & 15;
  int swz = (lm >> 1) & 3;
  int kb = lane >> 4;                  // 0..3 (k block of 8)
  int pos = (kb ^ swz) * 8;            // mirrored swizzle at read time
  int warow = (w >> 1) * 64;
  int wbrow = (w & 1) * 64;
  f32x4 acc[4][4];
  #pragma unroll
  for (int i = 0; i < 4; ++i)
    #pragma unroll
    for (int j = 0; j < 4; ++j) {
      f32x4 zv = {0.f, 0.f, 0.f, 0.f};
      acc[i][j] = zv;
    }
  for (int k0 = 0; k0 < K; k0 += 32) {
    __syncthreads();
    #pragma unroll
    for (int t = 0; t < 2; ++t) {
      int r = (w * 2 + t) * 16 + lr;   // 0..127
      GLOAD_LDS16(A + (long)(mb + r) * K + k0 + gb * 8, As + (w * 2 + t) * 512);
      GLOAD_LDS16(B + (long)(nb + r) * K + k0 + gb * 8, Bs + (w * 2 + t) * 512);
    }
    __syncthreads();
    short8 af[4], bfr[4];
    #pragma unroll
    for (int i = 0; i < 4; ++i) {
      af[i]  = *reinterpret_cast<const short8*>(As + (warow + i * 16 + lm) * 32 + pos);
      bfr[i] = *reinterpret_cast<const short8*>(Bs + (wbrow + i * 16 + lm) * 32 + pos);
    }
    #pragma unroll
    for (int i = 0; i < 4; ++i)
      #pragma unroll
      for (int j = 0; j < 4; ++j)
        acc[i][j] = __builtin_amdgcn_mfma_f32_16x16x32_bf16(af[i], bfr[j], acc[i][j], 0, 0, 0);
  }
  int m0 = mb + warow;
  int n0 = nb + wbrow;
  int col = lane & 15;
  int r0 = (lane >> 4) * 4;
  #pragma unroll
  for (int i = 0; i < 4; ++i)
    #pragma unroll
    for (int j = 0; j < 4; ++j) {
      int n = n0 + j * 16 + col;
      if (n < N) {
        int nc = cpad ? ((n / 40) * 42 + (n - (n / 40) * 40) + 43) : n;
        #pragma unroll
        for (int r = 0; r < 4; ++r) {
          int m = m0 + i * 16 + r0 + r;
          if (m < M) {
            long mr = cpad ? ((long)((m / 40) * 42 + (m - (m / 40) * 40) + 43) * 1764)
                           : ((long)m * N);
            C[mr + nc] = acc[i][j][r];
          }
        }
      }
    }
}

// ---------------------------------------------------------------------------
// K4+K5 merged (branchless via padded G)
// ---------------------------------------------------------------------------
__global__ __launch_bounds__(256) void s1fuse1_kernel(const float* __restrict__ Gp,
                                                      const float* __restrict__ INV,
                                                      float* __restrict__ S2) {
  int p = blockIdx.x * 256 + threadIdx.x;
  if (p >= 1600) return;
  int q = blockIdx.y, z = blockIdx.z;
  const float* Gz = Gp + (long)z * GPAD_Z;
  float s = 0.f;
  #pragma unroll
  for (int d = -1; d <= 1; ++d) {
    int q2 = q + d, p2 = p + d;
    bool ok = ((unsigned)q2 < 1600u) && ((unsigned)p2 < 1600u);
    int q2c = ok ? q2 : 0;
    int p2c = ok ? p2 : 0;
    float wgt = ok ? INV[z * 1600 + q2c] : 0.f;
    int qi = q2c / 40, qj = q2c - qi * 40;
    int pi = p2c / 40, pj = p2c - pi * 40;
    const float* base = Gz + (long)(qi * 42 + qj + 43) * 1764 + (pi * 42 + pj + 43);
    float t = 0.f;
    #pragma unroll
    for (int di = -1; di <= 1; ++di)
      #pragma unroll
      for (int dj = -1; dj <= 1; ++dj)
        t += base[(long)(di * 42 + dj) * 1765];
    s += t * wgt;
  }
  S2[((long)z * 1600 + q) * 1600 + p] = s;
}

// ---------------------------------------------------------------------------
// K6: fuse pass 2 — diagonal 3-tap in column-major-flattened coords
// ---------------------------------------------------------------------------
__global__ __launch_bounds__(256) void fuse2_kernel(const float* __restrict__ S2,
                                                    float* __restrict__ S3) {
  int p = blockIdx.x * 256 + threadIdx.x;
  if (p >= 1600) return;
  int q = blockIdx.y, z = blockIdx.z;
  const float* S = S2 + (long)z * 2560000;
  int il = q / 40, jl = q - il * 40;
  int im = p / 40, jm = p - im * 40;
  int u = jl * 40 + il, v = jm * 40 + im;
  float s = 0.f;
  #pragma unroll
  for (int d = -1; d <= 1; ++d) {
    int u2 = u + d, v2 = v + d;
    if (u2 >= 0 && u2 < 1600 && v2 >= 0 && v2 < 1600) {
      int q2 = (u2 % 40) * 40 + u2 / 40;
      int p2 = (v2 % 40) * 40 + v2 / 40;
      s += S[(long)q2 * 1600 + p2];
    }
  }
  S3[((long)z * 1600 + q) * 1600 + p] = s;
}

// ---------------------------------------------------------------------------
// K7a: softmax partials over q-chunks of 200, per (z,p)
// ---------------------------------------------------------------------------
__global__ __launch_bounds__(256) void smax_part(const float* __restrict__ S3,
                                                 float* __restrict__ Pm,
                                                 float* __restrict__ Ps) {
  int z = blockIdx.z, qc = blockIdx.y;
  int pl = threadIdx.x & 63;
  int ql = threadIdx.x >> 6;
  int p = blockIdx.x * 64 + pl;
  const float* S = S3 + (long)z * 2560000;
  float m = -1e30f, s = 0.f;
  for (int i = 0; i < 50; ++i) {
    int q = qc * 200 + i * 4 + ql;
    float x = 10.f * S[(long)q * 1600 + p];
    if (x > m) { s *= __expf(m - x); m = x; }
    s += __expf(x - m);
  }
  __shared__ float lm[4][64], ls[4][64];
  lm[ql][pl] = m;
  ls[ql][pl] = s;
  __syncthreads();
  if (ql == 0) {
    float M = m, SS = s;
    #pragma unroll
    for (int j = 1; j < 4; ++j) {
      float mj = lm[j][pl], sj = ls[j][pl];
      if (mj > M) { SS = SS * __expf(M - mj) + sj; M = mj; }
      else SS += sj * __expf(mj - M);
    }
    Pm[((long)z * 8 + qc) * 1600 + p] = M;
    Ps[((long)z * 8 + qc) * 1600 + p] = SS;
  }
}

// ---------------------------------------------------------------------------
// K7b: combine partials (folded, per p) -> normalize S3 -> bf16 ->
// LDS-transpose -> AT[p][q]
// ---------------------------------------------------------------------------
__global__ __launch_bounds__(256) void smax_write(const float* __restrict__ S3,
                                                  const float* __restrict__ Pm,
                                                  const float* __restrict__ Ps,
                                                  bf16* __restrict__ AT) {
  int z = blockIdx.z;
  int p0 = blockIdx.x * 64, q0 = blockIdx.y * 64;
  int pl = threadIdx.x & 63, ql = threadIdx.x >> 6;
  __shared__ float lfm[64], lfs[64];
  if (ql == 0) {
    int p = p0 + pl;
    float M = -1e30f;
    #pragma unroll
    for (int c = 0; c < 8; ++c) M = fmaxf(M, Pm[((long)z * 8 + c) * 1600 + p]);
    float S = 0.f;
    #pragma unroll
    for (int c = 0; c < 8; ++c)
      S += Ps[((long)z * 8 + c) * 1600 + p] * __expf(Pm[((long)z * 8 + c) * 1600 + p] - M);
    lfm[pl] = M;
    lfs[pl] = 1.f / S;
  }
  __syncthreads();
  __shared__ ushort_t T[64][66];
  float fm = lfm[pl];
  float fs = lfs[pl];
  const float* S = S3 + (long)z * 2560000;
  #pragma unroll
  for (int i = 0; i < 16; ++i) {
    int qq = ql + i * 4;
    float x = 10.f * S[(long)(q0 + qq) * 1600 + p0 + pl];
    bf16 h = __float2bfloat16(__expf(x - fm) * fs);
    T[pl][qq] = *reinterpret_cast<ushort_t*>(&h);
  }
  __syncthreads();
  int rp = threadIdx.x >> 5;  // 0..7
  int j = threadIdx.x & 31;
  #pragma unroll
  for (int pass = 0; pass < 8; ++pass) {
    int row = pass * 8 + rp;
    unsigned int vv = (unsigned int)T[row][2 * j] | ((unsigned int)T[row][2 * j + 1] << 16);
    *reinterpret_cast<unsigned int*>(AT + ((long)z * 1664 + p0 + row) * 1600 + q0 + 2 * j) = vv;
  }
}

// ---------------------------------------------------------------------------
// K8: RAWPT[z][(c,i,j)][q] = bf16(raw[b][c][2qi+i-1][2qj+j-1])
// ---------------------------------------------------------------------------
__global__ __launch_bounds__(256) void rawpt_kernel(const float* __restrict__ rawL,
                                                    const float* __restrict__ rawR,
                                                    bf16* __restrict__ RAWPT) {
  int z = blockIdx.z;
  int r = blockIdx.y * 4 + (threadIdx.x >> 6);
  int q = blockIdx.x * 64 + (threadIdx.x & 63);
  const float* raw = ((z < 2) ? rawL : rawR) + (long)(z & 1) * 819200;
  int c = r >> 4, i = (r >> 2) & 3, j = r & 3;
  int qi = q / 40, qj = q - qi * 40;
  int y = 2 * qi + i - 1, x = 2 * qj + j - 1;
  float v = 0.f;
  if (y >= 0 && y < 80 && x >= 0 && x < 80) v = raw[((long)c * 80 + y) * 80 + x];
  RAWPT[((long)z * 2048 + r) * 1600 + q] = __float2bfloat16(v);
}

// ---------------------------------------------------------------------------
// K10: overlap-add paste (2x2 valid (im,jm) per (y,x)), /4, cosine blend
// ---------------------------------------------------------------------------
__global__ __launch_bounds__(256) void paste_kernel(const float* __restrict__ Z,
                                                    float* __restrict__ out) {
  int idx = blockIdx.x * 256 + threadIdx.x;  // 0..1638399, exact
  int x = idx % 80;
  int t = idx / 80;
  int y = t % 80;
  t /= 80;
  int c = t % 128;
  int b = t / 128;
  int imA = (y - 1) >> 1, ipA = y - 2 * imA + 1;  // ipA in {2,3}
  int jmA = (x - 1) >> 1, jpA = x - 2 * jmA + 1;
  const long zs = 2048L * 1600;
  const float* ZL = Z + (long)b * zs;
  const float* ZR = Z + (long)(2 + b) * zs;
  float aL = 0.f, aR = 0.f;
  #pragma unroll
  for (int a = 0; a < 2; ++a) {
    int im = imA + a, ip = ipA - 2 * a;
    if (im < 0 || im > 39) continue;
    #pragma unroll
    for (int e = 0; e < 2; ++e) {
      int jm = jmA + e, jp = jpA - 2 * e;
      if (jm < 0 || jm > 39) continue;
      long off = (long)((c << 4) + ip * 4 + jp) * 1600 + im * 40 + jm;
      aL += ZL[off];
      aR += ZR[off];
    }
  }
  float wx = 0.5f * (1.f + cosf(PI_F * x / 79.f));
  float wf = 0.5f * (1.f + cosf(PI_F * (79 - x) / 79.f));
  out[idx] = 0.25f * (wx * aL + wf * aR);
}

// ---------------------------------------------------------------------------
extern "C" void kernel_launch(void* const* d_in, const int* in_sizes, int n_in,
                              void* d_out, int out_size, void* d_ws, size_t ws_size,
                              hipStream_t stream) {
  const float* left  = (const float*)d_in[0];
  const float* right = (const float*)d_in[1];
  const float* mid   = (const float*)d_in[2];
  const float* rawL  = (const float*)d_in[3];
  const float* rawR  = (const float*)d_in[4];
  float* out = (float*)d_out;
  char* ws = (char*)d_ws;

  bf16*  PTe   = (bf16*)(ws + 0);              // [4][1664][384] bf16 (hi|lo|hi)
  bf16*  MTe   = (bf16*)(ws + 5111808);        // [2][1664][384] bf16 (hi|hi|lo)
  float* SQ    = (float*)(ws + 7667712);       // [4][1600]
  float* INV   = (float*)(ws + 7693312);       // [4][1600]
  float* Pm    = (float*)(ws + 7718912);       // [4][8][1600]
  float* Ps    = (float*)(ws + 7923712);       // [4][8][1600]
  float* X     = (float*)(ws + 8179712);       // 52.4 MB pool: Gpad -> S3 -> Z
  float* Y     = (float*)(ws + 60608512);      // 41.0 MB pool: S2 -> RAWPT
  bf16*  AT    = (bf16*)(ws + 101568512);      // [4][1664][1600] bf16 (ends ~122.9MB)
  bf16*  RAWPT = (bf16*)Y;                     // overlay (26.2 MB <= 41.0 MB)

  prep_pt<<<dim3(1600, 6, 1), 128, 0, stream>>>(left, right, mid, PTe, MTe, SQ);
  invn_kernel<<<25, 256, 0, stream>>>(SQ, INV);
  hipMemsetAsync(X, 0, (size_t)4 * GPAD_Z * sizeof(float), stream);
  // Gram via three-term double-bf16 MFMA (K=384), writing padded 4D layout:
  // (169 tiles, not %8 -> swizzle is identity here)
  gemm_nt<<<dim3(13, 13, 4), 256, 0, stream>>>(PTe, MTe, X, 1600, 1600, 384,
                                               1664L * 384, 1664L * 384, GPAD_Z, 1, 1);
  s1fuse1_kernel<<<dim3(7, 1600, 4), 256, 0, stream>>>(X, INV, Y);  // Gpad -> S2
  fuse2_kernel<<<dim3(7, 1600, 4), 256, 0, stream>>>(Y, X);         // S2 -> S3
  smax_part<<<dim3(25, 8, 4), 256, 0, stream>>>(X, Pm, Ps);
  smax_write<<<dim3(25, 25, 4), 256, 0, stream>>>(X, Pm, Ps, AT);   // S3 -> AT
  rawpt_kernel<<<dim3(25, 512, 4), 256, 0, stream>>>(rawL, rawR, RAWPT);  // S2 dead
  // Deconv: 208 tiles -> XCD swizzle active (each XCD owns contiguous M-chunk)
  gemm_nt<<<dim3(16, 13, 4), 256, 0, stream>>>(RAWPT, AT, X, 2048, 1600, 1600,
                                               2048L * 1600, 1664L * 1600, 2048L * 1600, 0, 0);
  paste_kernel<<<6400, 256, 0, stream>>>(X, out);
}

// Round 13
// 352.703 us; speedup vs baseline: 1.0271x; 1.0271x over previous
//
#include <hip/hip_runtime.h>
#include <hip/hip_bf16.h>

typedef __hip_bfloat16 bf16;
typedef __attribute__((ext_vector_type(8))) short short8;
typedef __attribute__((ext_vector_type(4))) float f32x4;
typedef unsigned short ushort_t;

#define PI_F 3.14159265358979323846f
#define GPAD_Z 3111696L  // 1764*1764

#define GLOAD_LDS16(gp, lp)                                                    \
  __builtin_amdgcn_global_load_lds(                                            \
      (const __attribute__((address_space(1))) unsigned int*)(gp),             \
      (__attribute__((address_space(3))) unsigned int*)(lp), 16, 0, 0)

// ---------------------------------------------------------------------------
// K1: downsample (::2,::2) + transpose to [slice][q][384] bf16 with the
// three-term double-bf16 layout:
//   A-side (PTe): [hi | lo | hi],  B-side (MTe): [hi | hi | lo]
// so dot_{k<384} = hiA·hiB + loA·hiB + hiA·loB  (only loA·loB ~2^-18 dropped).
// Also per-pixel squared channel norms SQ[z][q] (fp32) for left/right.
// ---------------------------------------------------------------------------
__global__ __launch_bounds__(128) void prep_pt(const float* __restrict__ left,
                                               const float* __restrict__ right,
                                               const float* __restrict__ mid,
                                               bf16* __restrict__ PTe,
                                               bf16* __restrict__ MTe,
                                               float* __restrict__ SQ) {
  int q = blockIdx.x;          // 0..1599
  int y = blockIdx.y;          // 0..5
  int c = threadIdx.x;         // 0..127
  int qi = q / 40, qj = q - qi * 40;
  const float* src;
  bf16* dst;
  int b;
  bool aside = (y < 4);
  if (aside) {
    b = y & 1;
    src = (y < 2) ? left : right;
    dst = PTe + (long)y * 1664 * 384;
  } else {
    b = y - 4;
    src = mid;
    dst = MTe + (long)(y - 4) * 1664 * 384;
  }
  float v = src[(((long)b * 128 + c) * 80 + 2 * qi) * 80 + 2 * qj];
  bf16 hi = __float2bfloat16(v);
  bf16 lo = __float2bfloat16(v - __bfloat162float(hi));
  if (aside) {
    dst[(long)q * 384 + c] = hi;
    dst[(long)q * 384 + 128 + c] = lo;
    dst[(long)q * 384 + 256 + c] = hi;
  } else {
    dst[(long)q * 384 + c] = hi;
    dst[(long)q * 384 + 128 + c] = hi;
    dst[(long)q * 384 + 256 + c] = lo;
  }
  if (aside) {
    __shared__ float red[128];
    red[c] = v * v;
    __syncthreads();
    for (int s = 64; s > 0; s >>= 1) {
      if (c < s) red[c] += red[c + s];
      __syncthreads();
    }
    if (c == 0) SQ[y * 1600 + q] = red[0];
  }
}

// ---------------------------------------------------------------------------
// K2: invN[z][q] = rsqrt( 3x3 box of SQ (zero-padded) + 1152*EPS )
// ---------------------------------------------------------------------------
__global__ void invn_kernel(const float* __restrict__ SQ, float* __restrict__ INV) {
  int idx = blockIdx.x * 256 + threadIdx.x;
  if (idx >= 6400) return;
  int z = idx / 1600, q = idx - z * 1600;
  int qi = q / 40, qj = q - qi * 40;
  float s = 0.1152f;  // 128*3*3 * 1e-4
  #pragma unroll
  for (int di = -1; di <= 1; ++di)
    #pragma unroll
    for (int dj = -1; dj <= 1; ++dj) {
      int a = qi + di, b = qj + dj;
      if (a >= 0 && a < 40 && b >= 0 && b < 40) s += SQ[z * 1600 + a * 40 + b];
    }
  INV[idx] = rsqrtf(s);
}

// ---------------------------------------------------------------------------
// K2b: zero only the pad cells of Gpad ([42,42,42,42] layout, 1764x1764/z)
// pad = cells with row%42 in {0,41} or col%42 in {0,41} (8.8 MB vs 50 MB full)
// ---------------------------------------------------------------------------
__global__ __launch_bounds__(256) void padzero_kernel(float* __restrict__ Gp) {
  int row = blockIdx.x;   // 0..1763
  int z = blockIdx.y;     // 0..3
  float* R = Gp + (long)z * GPAD_Z + (long)row * 1764;
  int r42 = row % 42;
  if (r42 == 0 || r42 == 41) {
    for (int c = threadIdx.x; c < 1764; c += 256) R[c] = 0.f;
  } else {
    for (int i = threadIdx.x; i < 84; i += 256) {
      int c = (i >> 1) * 42 + ((i & 1) ? 41 : 0);
      R[c] = 0.f;
    }
  }
}

// ---------------------------------------------------------------------------
// K3/K9: bf16 MFMA GEMM (m97 structure, BK=32, VGPR-64 epilogue — round-11
// exact, known-good 78.5 µs; XCD swizzle removed: measured +4 µs, +37% fetch).
// bmod=1: B slice index = z&1. cpad=1: write C into padded [42,42,42,42].
// ---------------------------------------------------------------------------
__global__ __launch_bounds__(256) void gemm_nt(const bf16* __restrict__ A,
                                               const bf16* __restrict__ B,
                                               float* __restrict__ C,
                                               int M, int N, int K,
                                               long Az, long Bz, long Cz,
                                               int bmod, int cpad) {
  int z = blockIdx.z;
  A += (long)z * Az;
  B += (long)(bmod ? (z & 1) : z) * Bz;
  C += (long)z * Cz;
  __shared__ bf16 As[128 * 32];  // row-major [row][32], 64 B rows, 8 KB
  __shared__ bf16 Bs[128 * 32];
  int lane = threadIdx.x & 63;
  int w = threadIdx.x >> 6;
  int mb = blockIdx.x * 128;
  int nb = blockIdx.y * 128;
  int lr = lane >> 2;
  int gb = (lane & 3) ^ ((lane >> 3) & 3);  // XOR swizzle at stage time
  int lm = lane & 15;
  int swz = (lm >> 1) & 3;
  int kb = lane >> 4;                  // 0..3 (k block of 8)
  int pos = (kb ^ swz) * 8;            // mirrored swizzle at read time
  int warow = (w >> 1) * 64;
  int wbrow = (w & 1) * 64;
  f32x4 acc[4][4];
  #pragma unroll
  for (int i = 0; i < 4; ++i)
    #pragma unroll
    for (int j = 0; j < 4; ++j) {
      f32x4 zv = {0.f, 0.f, 0.f, 0.f};
      acc[i][j] = zv;
    }
  for (int k0 = 0; k0 < K; k0 += 32) {
    __syncthreads();
    #pragma unroll
    for (int t = 0; t < 2; ++t) {
      int r = (w * 2 + t) * 16 + lr;   // 0..127
      GLOAD_LDS16(A + (long)(mb + r) * K + k0 + gb * 8, As + (w * 2 + t) * 512);
      GLOAD_LDS16(B + (long)(nb + r) * K + k0 + gb * 8, Bs + (w * 2 + t) * 512);
    }
    __syncthreads();
    short8 af[4], bfr[4];
    #pragma unroll
    for (int i = 0; i < 4; ++i) {
      af[i]  = *reinterpret_cast<const short8*>(As + (warow + i * 16 + lm) * 32 + pos);
      bfr[i] = *reinterpret_cast<const short8*>(Bs + (wbrow + i * 16 + lm) * 32 + pos);
    }
    #pragma unroll
    for (int i = 0; i < 4; ++i)
      #pragma unroll
      for (int j = 0; j < 4; ++j)
        acc[i][j] = __builtin_amdgcn_mfma_f32_16x16x32_bf16(af[i], bfr[j], acc[i][j], 0, 0, 0);
  }
  int m0 = mb + warow;
  int n0 = nb + wbrow;
  int col = lane & 15;
  int r0 = (lane >> 4) * 4;
  #pragma unroll
  for (int i = 0; i < 4; ++i)
    #pragma unroll
    for (int j = 0; j < 4; ++j) {
      int n = n0 + j * 16 + col;
      if (n < N) {
        int nc = cpad ? ((n / 40) * 42 + (n - (n / 40) * 40) + 43) : n;
        #pragma unroll
        for (int r = 0; r < 4; ++r) {
          int m = m0 + i * 16 + r0 + r;
          if (m < M) {
            long mr = cpad ? ((long)((m / 40) * 42 + (m - (m / 40) * 40) + 43) * 1764)
                           : ((long)m * N);
            C[mr + nc] = acc[i][j][r];
          }
        }
      }
    }
}

// ---------------------------------------------------------------------------
// K4+K5 merged (branchless via padded G)
// ---------------------------------------------------------------------------
__global__ __launch_bounds__(256) void s1fuse1_kernel(const float* __restrict__ Gp,
                                                      const float* __restrict__ INV,
                                                      float* __restrict__ S2) {
  int p = blockIdx.x * 256 + threadIdx.x;
  if (p >= 1600) return;
  int q = blockIdx.y, z = blockIdx.z;
  const float* Gz = Gp + (long)z * GPAD_Z;
  float s = 0.f;
  #pragma unroll
  for (int d = -1; d <= 1; ++d) {
    int q2 = q + d, p2 = p + d;
    bool ok = ((unsigned)q2 < 1600u) && ((unsigned)p2 < 1600u);
    int q2c = ok ? q2 : 0;
    int p2c = ok ? p2 : 0;
    float wgt = ok ? INV[z * 1600 + q2c] : 0.f;
    int qi = q2c / 40, qj = q2c - qi * 40;
    int pi = p2c / 40, pj = p2c - pi * 40;
    const float* base = Gz + (long)(qi * 42 + qj + 43) * 1764 + (pi * 42 + pj + 43);
    float t = 0.f;
    #pragma unroll
    for (int di = -1; di <= 1; ++di)
      #pragma unroll
      for (int dj = -1; dj <= 1; ++dj)
        t += base[(long)(di * 42 + dj) * 1765];
    s += t * wgt;
  }
  S2[((long)z * 1600 + q) * 1600 + p] = s;
}

// ---------------------------------------------------------------------------
// K6: fuse pass 2 — diagonal 3-tap in column-major-flattened coords
// ---------------------------------------------------------------------------
__global__ __launch_bounds__(256) void fuse2_kernel(const float* __restrict__ S2,
                                                    float* __restrict__ S3) {
  int p = blockIdx.x * 256 + threadIdx.x;
  if (p >= 1600) return;
  int q = blockIdx.y, z = blockIdx.z;
  const float* S = S2 + (long)z * 2560000;
  int il = q / 40, jl = q - il * 40;
  int im = p / 40, jm = p - im * 40;
  int u = jl * 40 + il, v = jm * 40 + im;
  float s = 0.f;
  #pragma unroll
  for (int d = -1; d <= 1; ++d) {
    int u2 = u + d, v2 = v + d;
    if (u2 >= 0 && u2 < 1600 && v2 >= 0 && v2 < 1600) {
      int q2 = (u2 % 40) * 40 + u2 / 40;
      int p2 = (v2 % 40) * 40 + v2 / 40;
      s += S[(long)q2 * 1600 + p2];
    }
  }
  S3[((long)z * 1600 + q) * 1600 + p] = s;
}

// ---------------------------------------------------------------------------
// K7a: softmax partials over q-chunks of 200, per (z,p)
// ---------------------------------------------------------------------------
__global__ __launch_bounds__(256) void smax_part(const float* __restrict__ S3,
                                                 float* __restrict__ Pm,
                                                 float* __restrict__ Ps) {
  int z = blockIdx.z, qc = blockIdx.y;
  int pl = threadIdx.x & 63;
  int ql = threadIdx.x >> 6;
  int p = blockIdx.x * 64 + pl;
  const float* S = S3 + (long)z * 2560000;
  float m = -1e30f, s = 0.f;
  for (int i = 0; i < 50; ++i) {
    int q = qc * 200 + i * 4 + ql;
    float x = 10.f * S[(long)q * 1600 + p];
    if (x > m) { s *= __expf(m - x); m = x; }
    s += __expf(x - m);
  }
  __shared__ float lm[4][64], ls[4][64];
  lm[ql][pl] = m;
  ls[ql][pl] = s;
  __syncthreads();
  if (ql == 0) {
    float M = m, SS = s;
    #pragma unroll
    for (int j = 1; j < 4; ++j) {
      float mj = lm[j][pl], sj = ls[j][pl];
      if (mj > M) { SS = SS * __expf(M - mj) + sj; M = mj; }
      else SS += sj * __expf(mj - M);
    }
    Pm[((long)z * 8 + qc) * 1600 + p] = M;
    Ps[((long)z * 8 + qc) * 1600 + p] = SS;
  }
}

// ---------------------------------------------------------------------------
// K7b: combine partials (folded, per p) -> normalize S3 -> bf16 ->
// LDS-transpose -> AT[p][q]
// ---------------------------------------------------------------------------
__global__ __launch_bounds__(256) void smax_write(const float* __restrict__ S3,
                                                  const float* __restrict__ Pm,
                                                  const float* __restrict__ Ps,
                                                  bf16* __restrict__ AT) {
  int z = blockIdx.z;
  int p0 = blockIdx.x * 64, q0 = blockIdx.y * 64;
  int pl = threadIdx.x & 63, ql = threadIdx.x >> 6;
  __shared__ float lfm[64], lfs[64];
  if (ql == 0) {
    int p = p0 + pl;
    float M = -1e30f;
    #pragma unroll
    for (int c = 0; c < 8; ++c) M = fmaxf(M, Pm[((long)z * 8 + c) * 1600 + p]);
    float S = 0.f;
    #pragma unroll
    for (int c = 0; c < 8; ++c)
      S += Ps[((long)z * 8 + c) * 1600 + p] * __expf(Pm[((long)z * 8 + c) * 1600 + p] - M);
    lfm[pl] = M;
    lfs[pl] = 1.f / S;
  }
  __syncthreads();
  __shared__ ushort_t T[64][66];
  float fm = lfm[pl];
  float fs = lfs[pl];
  const float* S = S3 + (long)z * 2560000;
  #pragma unroll
  for (int i = 0; i < 16; ++i) {
    int qq = ql + i * 4;
    float x = 10.f * S[(long)(q0 + qq) * 1600 + p0 + pl];
    bf16 h = __float2bfloat16(__expf(x - fm) * fs);
    T[pl][qq] = *reinterpret_cast<ushort_t*>(&h);
  }
  __syncthreads();
  int rp = threadIdx.x >> 5;  // 0..7
  int j = threadIdx.x & 31;
  #pragma unroll
  for (int pass = 0; pass < 8; ++pass) {
    int row = pass * 8 + rp;
    unsigned int vv = (unsigned int)T[row][2 * j] | ((unsigned int)T[row][2 * j + 1] << 16);
    *reinterpret_cast<unsigned int*>(AT + ((long)z * 1664 + p0 + row) * 1600 + q0 + 2 * j) = vv;
  }
}

// ---------------------------------------------------------------------------
// K8: RAWPT[z][(c,i,j)][q] = bf16(raw[b][c][2qi+i-1][2qj+j-1])
// ---------------------------------------------------------------------------
__global__ __launch_bounds__(256) void rawpt_kernel(const float* __restrict__ rawL,
                                                    const float* __restrict__ rawR,
                                                    bf16* __restrict__ RAWPT) {
  int z = blockIdx.z;
  int r = blockIdx.y * 4 + (threadIdx.x >> 6);
  int q = blockIdx.x * 64 + (threadIdx.x & 63);
  const float* raw = ((z < 2) ? rawL : rawR) + (long)(z & 1) * 819200;
  int c = r >> 4, i = (r >> 2) & 3, j = r & 3;
  int qi = q / 40, qj = q - qi * 40;
  int y = 2 * qi + i - 1, x = 2 * qj + j - 1;
  float v = 0.f;
  if (y >= 0 && y < 80 && x >= 0 && x < 80) v = raw[((long)c * 80 + y) * 80 + x];
  RAWPT[((long)z * 2048 + r) * 1600 + q] = __float2bfloat16(v);
}

// ---------------------------------------------------------------------------
// K10: overlap-add paste (2x2 valid (im,jm) per (y,x)), /4, cosine blend
// ---------------------------------------------------------------------------
__global__ __launch_bounds__(256) void paste_kernel(const float* __restrict__ Z,
                                                    float* __restrict__ out) {
  int idx = blockIdx.x * 256 + threadIdx.x;  // 0..1638399, exact
  int x = idx % 80;
  int t = idx / 80;
  int y = t % 80;
  t /= 80;
  int c = t % 128;
  int b = t / 128;
  int imA = (y - 1) >> 1, ipA = y - 2 * imA + 1;  // ipA in {2,3}
  int jmA = (x - 1) >> 1, jpA = x - 2 * jmA + 1;
  const long zs = 2048L * 1600;
  const float* ZL = Z + (long)b * zs;
  const float* ZR = Z + (long)(2 + b) * zs;
  float aL = 0.f, aR = 0.f;
  #pragma unroll
  for (int a = 0; a < 2; ++a) {
    int im = imA + a, ip = ipA - 2 * a;
    if (im < 0 || im > 39) continue;
    #pragma unroll
    for (int e = 0; e < 2; ++e) {
      int jm = jmA + e, jp = jpA - 2 * e;
      if (jm < 0 || jm > 39) continue;
      long off = (long)((c << 4) + ip * 4 + jp) * 1600 + im * 40 + jm;
      aL += ZL[off];
      aR += ZR[off];
    }
  }
  float wx = 0.5f * (1.f + cosf(PI_F * x / 79.f));
  float wf = 0.5f * (1.f + cosf(PI_F * (79 - x) / 79.f));
  out[idx] = 0.25f * (wx * aL + wf * aR);
}

// ---------------------------------------------------------------------------
extern "C" void kernel_launch(void* const* d_in, const int* in_sizes, int n_in,
                              void* d_out, int out_size, void* d_ws, size_t ws_size,
                              hipStream_t stream) {
  const float* left  = (const float*)d_in[0];
  const float* right = (const float*)d_in[1];
  const float* mid   = (const float*)d_in[2];
  const float* rawL  = (const float*)d_in[3];
  const float* rawR  = (const float*)d_in[4];
  float* out = (float*)d_out;
  char* ws = (char*)d_ws;

  bf16*  PTe   = (bf16*)(ws + 0);              // [4][1664][384] bf16 (hi|lo|hi)
  bf16*  MTe   = (bf16*)(ws + 5111808);        // [2][1664][384] bf16 (hi|hi|lo)
  float* SQ    = (float*)(ws + 7667712);       // [4][1600]
  float* INV   = (float*)(ws + 7693312);       // [4][1600]
  float* Pm    = (float*)(ws + 7718912);       // [4][8][1600]
  float* Ps    = (float*)(ws + 7923712);       // [4][8][1600]
  float* X     = (float*)(ws + 8179712);       // 52.4 MB pool: Gpad -> S3 -> Z
  float* Y     = (float*)(ws + 60608512);      // 41.0 MB pool: S2 -> RAWPT
  bf16*  AT    = (bf16*)(ws + 101568512);      // [4][1664][1600] bf16 (ends ~122.9MB)
  bf16*  RAWPT = (bf16*)Y;                     // overlay (26.2 MB <= 41.0 MB)

  prep_pt<<<dim3(1600, 6, 1), 128, 0, stream>>>(left, right, mid, PTe, MTe, SQ);
  invn_kernel<<<25, 256, 0, stream>>>(SQ, INV);
  padzero_kernel<<<dim3(1764, 4), 256, 0, stream>>>(X);
  // Gram via three-term double-bf16 MFMA (K=384), writing padded 4D layout:
  gemm_nt<<<dim3(13, 13, 4), 256, 0, stream>>>(PTe, MTe, X, 1600, 1600, 384,
                                               1664L * 384, 1664L * 384, GPAD_Z, 1, 1);
  s1fuse1_kernel<<<dim3(7, 1600, 4), 256, 0, stream>>>(X, INV, Y);  // Gpad -> S2
  fuse2_kernel<<<dim3(7, 1600, 4), 256, 0, stream>>>(Y, X);         // S2 -> S3
  smax_part<<<dim3(25, 8, 4), 256, 0, stream>>>(X, Pm, Ps);
  smax_write<<<dim3(25, 25, 4), 256, 0, stream>>>(X, Pm, Ps, AT);   // S3 -> AT
  rawpt_kernel<<<dim3(25, 512, 4), 256, 0, stream>>>(rawL, rawR, RAWPT);  // S2 dead
  gemm_nt<<<dim3(16, 13, 4), 256, 0, stream>>>(RAWPT, AT, X, 2048, 1600, 1600,
                                               2048L * 1600, 1664L * 1600, 2048L * 1600, 0, 0);
  paste_kernel<<<6400, 256, 0, stream>>>(X, out);
}